// Round 14
// baseline (794.583 us; speedup 1.0000x reference)
//
#include <hip/hip_runtime.h>
#include <math.h>

#define NA 100000
#define NB 100000
#define NTOT 200000
#define EE 400000      // edges per type
#define TDIM 100       // time encoder dim
#define NTILE (EE / 16)

typedef short bf16x8 __attribute__((ext_vector_type(8)));
typedef float f32x4 __attribute__((ext_vector_type(4)));

// ---------- helpers ----------
__device__ __forceinline__ float gelu_exact(float x) {
    return 0.5f * x * (1.0f + erff(x * 0.70710678118654752f));
}
__device__ __forceinline__ unsigned bf16rne(float f) {
    unsigned u = __float_as_uint(f);
    return (u + 0x7fffu + ((u >> 16) & 1u)) >> 16;
}
__device__ __forceinline__ unsigned pack_bf2(float lo, float hi) {
    return bf16rne(lo) | (bf16rne(hi) << 16);
}
__device__ __forceinline__ float bf_lo(unsigned u) { return __uint_as_float(u << 16); }
__device__ __forceinline__ float bf_hi(unsigned u) { return __uint_as_float(u & 0xffff0000u); }

// ---------- prologue: fusew (blocks 0..767) + wedget (768..831) ----------
__global__ __launch_bounds__(192) void weprep_kernel(
    const float* __restrict__ W_A, const float* __restrict__ b_A,
    const float* __restrict__ W_B, const float* __restrict__ b_B,
    const float* __restrict__ Wk_rel, const float* __restrict__ Wv_rel,
    const float* __restrict__ W_edge,
    unsigned short* __restrict__ WfA, float* __restrict__ bfA,
    unsigned short* __restrict__ WfB, float* __restrict__ bfB,
    unsigned short* __restrict__ Wet)
{
    const int blk = blockIdx.x;
    if (blk < 768) {
        if (threadIdx.x >= 128) return;
        const int et = (blk >= 384) ? 1 : 0;
        const int c = blk - et * 384;
        const int i = threadIdx.x;
        const float* __restrict__ W = et ? W_B : W_A;
        const float* __restrict__ b = et ? b_B : b_A;
        unsigned short* __restrict__ Wf_t = et ? WfB : WfA;
        float* __restrict__ bf = et ? bfB : bfA;

        float acc = 0.f;
        if (c < 128) {
            const int h = c >> 6, e = c & 63;
            const float* __restrict__ Wr = Wk_rel + (long)(h * 2 + et) * 4096;
            for (int d = 0; d < 64; ++d) acc += W[i * 384 + h * 64 + d] * Wr[d * 64 + e];
        } else if (c < 256) {
            acc = W[i * 384 + c];
        } else {
            const int h = (c - 256) >> 6, e = (c - 256) & 63;
            const float* __restrict__ Wr = Wv_rel + (long)(h * 2 + et) * 4096;
            for (int d = 0; d < 64; ++d) acc += W[i * 384 + 256 + h * 64 + d] * Wr[d * 64 + e];
        }
        Wf_t[c * 128 + i] = (unsigned short)bf16rne(acc);
        if (i == 0) {
            float bacc = 0.f;
            if (c < 128) {
                const int h = c >> 6, e = c & 63;
                const float* __restrict__ Wr = Wk_rel + (long)(h * 2 + et) * 4096;
                for (int d = 0; d < 64; ++d) bacc += b[h * 64 + d] * Wr[d * 64 + e];
            } else if (c < 256) {
                bacc = b[c];
            } else {
                const int h = (c - 256) >> 6, e = (c - 256) & 63;
                const float* __restrict__ Wr = Wv_rel + (long)(h * 2 + et) * 4096;
                for (int d = 0; d < 64; ++d) bacc += b[256 + h * 64 + d] * Wr[d * 64 + e];
            }
            bf[c] = bacc;
        }
    } else {
        const int col = blk - 768;       // 0..63
        const int k = threadIdx.x;       // 0..191
        const float v = (k < 164) ? W_edge[k * 64 + col] : 0.f;
        Wet[col * 192 + k] = (unsigned short)bf16rne(v);
    }
}

// ---------- CSR count ----------
__global__ __launch_bounds__(256) void count_kernel(
    const int* __restrict__ eiAB, const int* __restrict__ eiBA, int* __restrict__ cnt)
{
    const int ee = blockIdx.x * 256 + threadIdx.x;
    if (ee >= 2 * EE) return;
    const int dst = (ee < EE) ? (eiAB[EE + ee] + NA) : eiBA[EE + (ee - EE)];
    atomicAdd(&cnt[dst], 1);
}

// ---------- CSR scan ----------
__global__ __launch_bounds__(1024) void scan1_kernel(
    const int* __restrict__ cnt, int* __restrict__ offsets, int* __restrict__ bsum)
{
    __shared__ int tmp[1024];
    const int t = threadIdx.x;
    const int i = blockIdx.x * 1024 + t;
    const int v = (i < NTOT) ? cnt[i] : 0;
    tmp[t] = v;
    __syncthreads();
    for (int off = 1; off < 1024; off <<= 1) {
        const int u = (t >= off) ? tmp[t - off] : 0;
        __syncthreads();
        tmp[t] += u;
        __syncthreads();
    }
    offsets[i] = tmp[t] - v;
    if (t == 1023) bsum[blockIdx.x] = tmp[1023];
}

__global__ __launch_bounds__(256) void scan2_kernel(
    const int* __restrict__ bsum, int* __restrict__ bbase, int nblk)
{
    __shared__ int tmp[256];
    const int t = threadIdx.x;
    const int v = (t < nblk) ? bsum[t] : 0;
    tmp[t] = v;
    __syncthreads();
    for (int off = 1; off < 256; off <<= 1) {
        const int u = (t >= off) ? tmp[t - off] : 0;
        __syncthreads();
        tmp[t] += u;
        __syncthreads();
    }
    bbase[t] = tmp[t] - v;
}

__global__ __launch_bounds__(1024) void scan3_kernel(
    int* __restrict__ offsets, const int* __restrict__ bbase, int* __restrict__ cnt)
{
    const int t = threadIdx.x;
    const int i = blockIdx.x * 1024 + t;
    const int o = offsets[i] + bbase[blockIdx.x];
    offsets[i] = o;
    if (i < NTOT) cnt[i] = o;
    if (blockIdx.x == 0 && t == 0) offsets[NTOT] = 2 * EE;
}

// fill: csr[pos] = {src, ee}, pos_map[ee] = pos
__global__ __launch_bounds__(256) void fill_kernel(
    const int* __restrict__ eiAB, const int* __restrict__ eiBA,
    int* __restrict__ cursor, int2* __restrict__ csr, int* __restrict__ pos_map)
{
    const int ee = blockIdx.x * 256 + threadIdx.x;
    if (ee >= 2 * EE) return;
    int src, dst;
    if (ee < EE) { src = eiAB[ee];               dst = eiAB[EE + ee] + NA; }
    else { const int e = ee - EE; src = eiBA[e] + NA; dst = eiBA[EE + e]; }
    const int pos = atomicAdd(&cursor[dst], 1);
    csr[pos] = make_int2(src, ee);
    pos_map[ee] = pos;
}

// ---------- P1 mega-kernel: kqv MFMA || edgefeat wave-MFMA (ef in CSR order) ----------
// 18750 blocks = 6 x 3125. role = b%6: {0,1}=kqv, {2..5}=edgefeat.
#define BM 32
__global__ __launch_bounds__(256) void phase1_kernel(
    const float* __restrict__ x_A, const float* __restrict__ x_B,
    const unsigned short* __restrict__ WfA, const unsigned short* __restrict__ WfB,
    const float* __restrict__ bfA, const float* __restrict__ bfB,
    unsigned* __restrict__ q_u32, unsigned* __restrict__ kv_u32,
    const float* __restrict__ lu_A, const float* __restrict__ lu_B,
    const int* __restrict__ eiAB, const int* __restrict__ eiBA,
    const float* __restrict__ t_AB, const float* __restrict__ t_BA,
    const float* __restrict__ msg_AB, const float* __restrict__ msg_BA,
    const float* __restrict__ time_w, const float* __restrict__ time_b,
    const unsigned short* __restrict__ Wet, const float* __restrict__ b_edge,
    const int* __restrict__ pos_map,
    unsigned* __restrict__ ef_u32)
{
    __shared__ unsigned lds_u[6400];             // 25.6KB union
    const int b = blockIdx.x;
    const int role = b % 6;
    const int sub6 = b / 6;
    const int tid = threadIdx.x;
    const int lane = tid & 63;
    const int wv = tid >> 6;

    if (role < 2) {
        // ================= kqv =================
        const int kblk = sub6 * 2 + role;        // 0..6249
        const bool isA = (kblk < NA / BM);
        const int blk = isA ? kblk : (kblk - NA / BM);
        const float* __restrict__ x = isA ? x_A : x_B;
        const unsigned short* __restrict__ Wf_t = isA ? WfA : WfB;
        const float* __restrict__ bf = isA ? bfA : bfB;
        const int node_off = isA ? 0 : NA;

        unsigned* xs = lds_u;                    // [32][68]
        unsigned* st = lds_u + 2176;             // [32][130]
        const int m = lane & 15;
        const int kq = lane >> 4;
        const int n0 = blk * BM;

        for (int idx = tid; idx < BM * 32; idx += 256) {
            const int n = idx >> 5, j4 = idx & 31;
            const float4 xv = *reinterpret_cast<const float4*>(x + (long)(n0 + n) * 128 + 4 * j4);
            xs[n * 68 + 2 * j4]     = pack_bf2(xv.x, xv.y);
            xs[n * 68 + 2 * j4 + 1] = pack_bf2(xv.z, xv.w);
        }
        __syncthreads();

        const int wq = wv * 96;
        f32x4 acc[2][6];
        #pragma unroll
        for (int mt = 0; mt < 2; ++mt)
            #pragma unroll
            for (int nt = 0; nt < 6; ++nt) acc[mt][nt] = (f32x4){0.f, 0.f, 0.f, 0.f};

        #pragma unroll
        for (int ks = 0; ks < 4; ++ks) {
            bf16x8 a[2], bfr[6];
            #pragma unroll
            for (int mt = 0; mt < 2; ++mt)
                a[mt] = *reinterpret_cast<const bf16x8*>(&xs[(mt * 16 + m) * 68 + ks * 16 + kq * 4]);
            #pragma unroll
            for (int nt = 0; nt < 6; ++nt) {
                const int col = wq + nt * 16 + m;
                bfr[nt] = *reinterpret_cast<const bf16x8*>(Wf_t + (long)col * 128 + ks * 32 + kq * 8);
            }
            #pragma unroll
            for (int mt = 0; mt < 2; ++mt)
                #pragma unroll
                for (int nt = 0; nt < 6; ++nt)
                    acc[mt][nt] = __builtin_amdgcn_mfma_f32_16x16x32_bf16(a[mt], bfr[nt], acc[mt][nt], 0, 0, 0);
        }
        __syncthreads();

        // ---- kv staging pass ----
        #pragma unroll
        for (int nt = 0; nt < 6; ++nt) {
            const int c = wq + nt * 16 + m;
            if (c < 128 || c >= 256) {
                const float bias_c = bf[c];
                const int dw = (c < 128) ? c : (c - 256 + 1);
                #pragma unroll
                for (int mt = 0; mt < 2; ++mt) {
                    #pragma unroll
                    for (int reg = 0; reg < 4; ++reg) {
                        const float v = acc[mt][nt][reg] + bias_c;
                        const float o = __shfl_xor(v, 1);
                        if (!(m & 1)) st[(mt * 16 + kq * 4 + reg) * 130 + dw] = pack_bf2(v, o);
                    }
                }
            }
        }
        __syncthreads();
        {
            const int n = tid >> 3;
            const long nb = node_off + n0 + n;
            const int d0 = (tid & 7) * 16;
            #pragma unroll
            for (int i = 0; i < 4; ++i) {
                uint4 w;
                w.x = st[n * 130 + d0 + i * 4 + 0];
                w.y = st[n * 130 + d0 + i * 4 + 1];
                w.z = st[n * 130 + d0 + i * 4 + 2];
                w.w = st[n * 130 + d0 + i * 4 + 3];
                *reinterpret_cast<uint4*>(kv_u32 + nb * 128 + d0 + i * 4) = w;
            }
        }
        __syncthreads();
        // ---- q staging pass ----
        #pragma unroll
        for (int nt = 0; nt < 6; ++nt) {
            const int c = wq + nt * 16 + m;
            if (c >= 128 && c < 256) {
                const float bias_c = bf[c];
                const int dw = (c - 128) >> 1;
                #pragma unroll
                for (int mt = 0; mt < 2; ++mt) {
                    #pragma unroll
                    for (int reg = 0; reg < 4; ++reg) {
                        const float v = acc[mt][nt][reg] + bias_c;
                        const float o = __shfl_xor(v, 1);
                        if (!(m & 1)) st[(mt * 16 + kq * 4 + reg) * 130 + dw] = pack_bf2(v, o);
                    }
                }
            }
        }
        __syncthreads();
        {
            const int n = tid >> 3;
            const long nb = node_off + n0 + n;
            const int dq = (tid & 7) * 8;
            #pragma unroll
            for (int i = 0; i < 2; ++i) {
                uint4 w;
                w.x = st[n * 130 + dq + i * 4 + 0];
                w.y = st[n * 130 + dq + i * 4 + 1];
                w.z = st[n * 130 + dq + i * 4 + 2];
                w.w = st[n * 130 + dq + i * 4 + 3];
                *reinterpret_cast<uint4*>(q_u32 + nb * 64 + dq + i * 4) = w;
            }
        }
    } else {
        // ================= edgefeat (wave-synchronous, CSR-ordered output) =================
        const int eblk = sub6 * 4 + (role - 2);  // 0..12499
        const int gw = eblk * 4 + wv;            // 0..49999
        const bool isAB = gw < NTILE;
        const int tile = isAB ? gw : gw - NTILE;
        const float* __restrict__ lu   = isAB ? lu_A : lu_B;
        const int* __restrict__ ei     = isAB ? eiAB : eiBA;
        const float* __restrict__ tvec = isAB ? t_AB : t_BA;
        const float* __restrict__ msg  = isAB ? msg_AB : msg_BA;
        const long out_off = isAB ? 0L : (long)EE;
        const long e0 = (long)tile * 16;

        unsigned* fw = lds_u + wv * 1600;        // [16][100] per wave

        // edge meta in lanes 0..15: rel_t gather + CSR position (both issued early)
        float rts_l = 0.f;
        int pos_l = 0;
        if (lane < 16) {
            rts_l = lu[ei[e0 + lane]] - tvec[e0 + lane];
            pos_l = pos_map[out_off + e0 + lane];
        }

        {
            const int e = lane >> 2, qt = lane & 3;
            const float* mp = msg + (e0 + e) * 64 + qt * 16;
            const float4 a0 = *reinterpret_cast<const float4*>(mp);
            const float4 a1 = *reinterpret_cast<const float4*>(mp + 4);
            const float4 a2 = *reinterpret_cast<const float4*>(mp + 8);
            const float4 a3 = *reinterpret_cast<const float4*>(mp + 12);
            uint2 w0, w1, w2, w3;
            w0.x = pack_bf2(a0.x, a0.y); w0.y = pack_bf2(a0.z, a0.w);
            w1.x = pack_bf2(a1.x, a1.y); w1.y = pack_bf2(a1.z, a1.w);
            w2.x = pack_bf2(a2.x, a2.y); w2.y = pack_bf2(a2.z, a2.w);
            w3.x = pack_bf2(a3.x, a3.y); w3.y = pack_bf2(a3.z, a3.w);
            *reinterpret_cast<uint2*>(&fw[e * 100 + 50 + qt * 8])     = w0;
            *reinterpret_cast<uint2*>(&fw[e * 100 + 50 + qt * 8 + 2]) = w1;
            *reinterpret_cast<uint2*>(&fw[e * 100 + 50 + qt * 8 + 4]) = w2;
            *reinterpret_cast<uint2*>(&fw[e * 100 + 50 + qt * 8 + 6]) = w3;
        }
        #pragma unroll
        for (int i = 0; i < 13; ++i) {
            const int idx = lane + (i << 6);
            if (idx < 800) {
                const int e = idx / 50, j = idx - e * 50;
                const float r = __shfl(rts_l, e);
                const float c0 = __cosf(fmaf(r, time_w[2 * j], time_b[2 * j]));
                const float c1 = __cosf(fmaf(r, time_w[2 * j + 1], time_b[2 * j + 1]));
                fw[e * 100 + j] = pack_bf2(c0, c1);
            }
        }
        #pragma unroll
        for (int i = 0; i < 5; ++i) {
            const int idx = lane + (i << 6);
            if (idx < 288) {
                const int e = idx / 18, j = idx - e * 18;
                fw[e * 100 + 82 + j] = 0u;
            }
        }
        asm volatile("s_waitcnt lgkmcnt(0)" ::: "memory");

        const int m = lane & 15;
        const int kq = lane >> 4;
        f32x4 acc[4];
        #pragma unroll
        for (int nf = 0; nf < 4; ++nf) acc[nf] = (f32x4){0.f, 0.f, 0.f, 0.f};

        #pragma unroll
        for (int ks = 0; ks < 6; ++ks) {
            const bf16x8 a = *reinterpret_cast<const bf16x8*>(&fw[m * 100 + ks * 16 + kq * 4]);
            #pragma unroll
            for (int nf = 0; nf < 4; ++nf) {
                const bf16x8 bb = *reinterpret_cast<const bf16x8*>(Wet + (long)(nf * 16 + m) * 192 + ks * 32 + kq * 8);
                acc[nf] = __builtin_amdgcn_mfma_f32_16x16x32_bf16(a, bb, acc[nf], 0, 0, 0);
            }
        }

        #pragma unroll
        for (int nf = 0; nf < 4; ++nf) {
            const int c = nf * 16 + m;
            const float bc = b_edge[c];
            #pragma unroll
            for (int reg = 0; reg < 4; ++reg) {
                const float v = acc[nf][reg] + bc;
                const float o = __shfl_xor(v, 1);
                const int pos = __shfl(pos_l, kq * 4 + reg);
                if (!(lane & 1)) {
                    ef_u32[(long)pos * 32 + (c >> 1)] = pack_bf2(v, o);
                }
            }
        }
    }
}

// ---------- gather: fused flash-softmax + gelu, 2 edges per wave, CSR-ordered ef ----------
// lane = 32*eh + 16*h + j : eh = edge slot, h = head, j = comp group (4 comps)
__global__ __launch_bounds__(256) void gather_kernel(
    const unsigned* __restrict__ qb, const uint4* __restrict__ kv,
    const unsigned* __restrict__ ef,
    const int* __restrict__ offsets, const int2* __restrict__ csr,
    const float* __restrict__ p_rel_AB, const float* __restrict__ p_rel_BA,
    unsigned* __restrict__ g)
{
    const int lane = threadIdx.x & 63;
    const int wv = threadIdx.x >> 6;
    const int eh = lane >> 5;
    const int h = (lane >> 4) & 1;
    const int j = lane & 15;
    const int c = 16 * h + j;                    // dword-pair index 0..31
    const int d0 = blockIdx.x * 16 + wv * 4;     // 12500 blocks, exact
    const float sAB = p_rel_AB[h] * 0.125f;
    const float sBA = p_rel_BA[h] * 0.125f;

    for (int r = 0; r < 4; ++r) {
        const int d = d0 + r;
        const uint2 q2 = *reinterpret_cast<const uint2*>(qb + (long)d * 64 + 2 * c);
        float av0 = 0.f, av1 = 0.f, av2 = 0.f, av3 = 0.f;
        float ae00 = 0.f, ae01 = 0.f, ae10 = 0.f, ae11 = 0.f;
        float den = 0.f;
        const int beg = offsets[d], end = offsets[d + 1];
        for (int p0 = beg; p0 < end; p0 += 2) {
            const int p = p0 + eh;
            const bool valid = (p < end);
            const int pc = valid ? p : p0;
            const int2 se = csr[pc];
            const uint4 kvd = kv[(long)se.x * 32 + c];
            const unsigned efd = ef[(long)pc * 32 + c];      // sequential in CSR order
            float partial = fmaf(bf_lo(q2.x), bf_lo(kvd.x),
                            fmaf(bf_hi(q2.x), bf_hi(kvd.x),
                            fmaf(bf_lo(q2.y), bf_lo(kvd.z),
                                 bf_hi(q2.y) * bf_hi(kvd.z))));
            partial += __shfl_xor(partial, 1);
            partial += __shfl_xor(partial, 2);
            partial += __shfl_xor(partial, 4);
            partial += __shfl_xor(partial, 8);
            const float s = (se.y < EE) ? sAB : sBA;
            float e = valid ? expf(partial * s) : 0.f;
            const float ef0 = bf_lo(efd), ef1 = bf_hi(efd);
            const float e_oth = __shfl_xor(e, 16);
            const float w0 = h ? e_oth : e;      // head-0 softmax weight
            const float w1 = h ? e : e_oth;      // head-1 softmax weight
            av0 = fmaf(e, bf_lo(kvd.y), av0);
            av1 = fmaf(e, bf_hi(kvd.y), av1);
            av2 = fmaf(e, bf_lo(kvd.w), av2);
            av3 = fmaf(e, bf_hi(kvd.w), av3);
            ae00 = fmaf(w0, ef0, ae00);
            ae01 = fmaf(w0, ef1, ae01);
            ae10 = fmaf(w1, ef0, ae10);
            ae11 = fmaf(w1, ef1, ae11);
            den += e;
        }
        // merge the two edge-slot halves
        av0 += __shfl_xor(av0, 32);
        av1 += __shfl_xor(av1, 32);
        av2 += __shfl_xor(av2, 32);
        av3 += __shfl_xor(av3, 32);
        ae00 += __shfl_xor(ae00, 32);
        ae01 += __shfl_xor(ae01, 32);
        ae10 += __shfl_xor(ae10, 32);
        ae11 += __shfl_xor(ae11, 32);
        den += __shfl_xor(den, 32);

        const float inv = 1.f / (den + 1e-16f);          // own head's inverse denom
        const float inv_oth = __shfl_xor(inv, 16);
        const float inv0 = h ? inv_oth : inv;
        const float inv1 = h ? inv : inv_oth;

        if (eh == 0) {
            const float gv0 = gelu_exact(av0 * inv);
            const float gv1 = gelu_exact(av1 * inv);
            const float gv2 = gelu_exact(av2 * inv);
            const float gv3 = gelu_exact(av3 * inv);
            const float ge00 = gelu_exact(ae00 * inv0);
            const float ge01 = gelu_exact(ae01 * inv0);
            const float ge10 = gelu_exact(ae10 * inv1);
            const float ge11 = gelu_exact(ae11 * inv1);
            unsigned* gp = g + (long)d * 128;
            const int vb = h ? (64 + 2 * j) : (2 * j);   // v block dword base
            gp[vb]     = pack_bf2(gv0, gv1);
            gp[vb + 1] = pack_bf2(gv2, gv3);
            gp[32 + c] = pack_bf2(ge00, ge01);           // ef, head-0 block
            gp[96 + c] = pack_bf2(ge10, ge11);           // ef, head-1 block
        }
    }
}

// ---------- proj: MFMA out-projection (A and B in one grid), in-place over g ----------
__global__ __launch_bounds__(256) void proj_mfma_kernel(
    const short* __restrict__ g,
    const float* __restrict__ W_out_A, const float* __restrict__ b_out_A,
    const float* __restrict__ W_out_B, const float* __restrict__ b_out_B,
    const float* __restrict__ x_A, const float* __restrict__ x_B,
    const float* __restrict__ skip_A, const float* __restrict__ skip_B,
    float* __restrict__ out, int nblkA)
{
    const bool isA = ((int)blockIdx.x < nblkA);
    const int blk = isA ? blockIdx.x : (blockIdx.x - nblkA);
    const float* __restrict__ W_out = isA ? W_out_A : W_out_B;
    const float* __restrict__ b_out = isA ? b_out_A : b_out_B;
    const float* __restrict__ x = isA ? x_A : x_B;
    const float* __restrict__ skip = isA ? skip_A : skip_B;
    const int roff = isA ? 0 : NA;
    const int N = isA ? NA : NB;

    __shared__ unsigned short Wt[128 * 264];
    const int tid = threadIdx.x;
    const int lane = tid & 63;
    const int wv = tid >> 6;

    for (int idx = tid; idx < 256 * 128; idx += 256) {
        const int k = idx >> 7, n = idx & 127;
        Wt[n * 264 + k] = (unsigned short)bf16rne(W_out[idx]);
    }
    __syncthreads();

    const int m0 = roff + blk * 64 + wv * 16;
    const int rmax = roff + N - 1;
    const float ag = 1.f / (1.f + expf(-skip[0]));

    f32x4 acc[8];
    #pragma unroll
    for (int nf = 0; nf < 8; ++nf) acc[nf] = (f32x4){0.f, 0.f, 0.f, 0.f};

    const int arow = min(m0 + (lane & 15), rmax);
    const int kgrp = (lane >> 4) * 8;

    #pragma unroll
    for (int ks = 0; ks < 8; ++ks) {
        const bf16x8 a = *reinterpret_cast<const bf16x8*>(g + (long)arow * 256 + ks * 32 + kgrp);
        #pragma unroll
        for (int nf = 0; nf < 8; ++nf) {
            const bf16x8 b = *reinterpret_cast<const bf16x8*>(&Wt[(nf * 16 + (lane & 15)) * 264 + ks * 32 + kgrp]);
            acc[nf] = __builtin_amdgcn_mfma_f32_16x16x32_bf16(a, b, acc[nf], 0, 0, 0);
        }
    }

    #pragma unroll
    for (int nf = 0; nf < 8; ++nf) {
        const int col = nf * 16 + (lane & 15);
        const float bc = b_out[col];
        #pragma unroll
        for (int reg = 0; reg < 4; ++reg) {
            const int d = m0 + (lane >> 4) * 4 + reg;
            if (d <= rmax) {
                const float xv = x[(long)(d - roff) * 128 + col];
                out[(long)d * 128 + col] = fmaf(ag, acc[nf][reg] + bc, (1.f - ag) * xv);
            }
        }
    }
}

// ---------- launcher ----------
extern "C" void kernel_launch(void* const* d_in, const int* in_sizes, int n_in,
                              void* d_out, int out_size, void* d_ws, size_t ws_size,
                              hipStream_t stream) {
    const float* x_A     = (const float*)d_in[0];
    const float* x_B     = (const float*)d_in[1];
    const float* lu_A    = (const float*)d_in[2];
    const float* lu_B    = (const float*)d_in[3];
    const float* t_AB    = (const float*)d_in[4];
    const float* t_BA    = (const float*)d_in[5];
    const float* msg_AB  = (const float*)d_in[6];
    const float* msg_BA  = (const float*)d_in[7];
    const float* W_kqv_A = (const float*)d_in[8];
    const float* b_kqv_A = (const float*)d_in[9];
    const float* W_kqv_B = (const float*)d_in[10];
    const float* b_kqv_B = (const float*)d_in[11];
    const float* Wk_rel  = (const float*)d_in[12];
    const float* Wv_rel  = (const float*)d_in[13];
    const float* W_edge  = (const float*)d_in[14];
    const float* b_edge  = (const float*)d_in[15];
    const float* W_out_A = (const float*)d_in[16];
    const float* b_out_A = (const float*)d_in[17];
    const float* W_out_B = (const float*)d_in[18];
    const float* b_out_B = (const float*)d_in[19];
    const float* skip_A  = (const float*)d_in[20];
    const float* skip_B  = (const float*)d_in[21];
    const float* p_rel_AB= (const float*)d_in[22];
    const float* p_rel_BA= (const float*)d_in[23];
    const float* time_w  = (const float*)d_in[24];
    const float* time_b  = (const float*)d_in[25];
    const int*   eiAB    = (const int*)d_in[26];
    const int*   eiBA    = (const int*)d_in[27];
    float* out = (float*)d_out;

    // workspace layout (~268 MB)
    unsigned* q_bf  = (unsigned*)d_ws;                  // 12.8M u32
    unsigned* kvbuf = q_bf + 12800000;                  // 25.6M u32
    unsigned* efbuf = kvbuf + 25600000;                 // 25.6M u32 (CSR-ordered)
    int* cnt      = (int*)(efbuf + 25600000);           // 200000
    int* offsets  = cnt + 200000;                       // 210000
    int* csr_base = offsets + 210000;                   // 1.6M ints = 800000 int2
    int2* csr     = (int2*)csr_base;
    int* pos_map  = csr_base + 1600000;                 // 800000 ints
    unsigned short* WfA = (unsigned short*)(pos_map + 800000);  // 49152 bf16
    unsigned short* WfB = WfA + 49152;                  // 49152 bf16
    float* bfA    = (float*)(WfB + 49152);              // 384
    float* bfB    = bfA + 384;                          // 384
    int* bsum     = (int*)(bfB + 384);                  // 256
    int* bbase    = bsum + 256;                         // 256
    unsigned short* Wet = (unsigned short*)(bbase + 256); // 12288 bf16

    (void)hipMemsetAsync(cnt, 0, (size_t)200000 * 4, stream);

    // prologue: fused weight prep (fusew || wedget)
    weprep_kernel<<<832, 192, 0, stream>>>(W_kqv_A, b_kqv_A, W_kqv_B, b_kqv_B,
                                           Wk_rel, Wv_rel, W_edge,
                                           WfA, bfA, WfB, bfB, Wet);

    // CSR build (must precede phase1: edgefeat writes ef in CSR order)
    count_kernel<<<(2 * EE + 255) / 256, 256, 0, stream>>>(eiAB, eiBA, cnt);
    scan1_kernel<<<196, 1024, 0, stream>>>(cnt, offsets, bsum);
    scan2_kernel<<<1, 256, 0, stream>>>(bsum, bbase, 196);
    scan3_kernel<<<196, 1024, 0, stream>>>(offsets, bbase, cnt);
    fill_kernel<<<(2 * EE + 255) / 256, 256, 0, stream>>>(eiAB, eiBA, cnt, csr, pos_map);

    // P1: kqv || edgefeat, co-scheduled (18750 = 6*3125 blocks)
    phase1_kernel<<<18750, 256, 0, stream>>>(x_A, x_B, WfA, WfB, bfA, bfB, q_bf, kvbuf,
                                             lu_A, lu_B, eiAB, eiBA, t_AB, t_BA,
                                             msg_AB, msg_BA, time_w, time_b, Wet, b_edge,
                                             pos_map, efbuf);

    gather_kernel<<<NTOT / 16, 256, 0, stream>>>(q_bf, (const uint4*)kvbuf, efbuf,
                                                 offsets, csr,
                                                 p_rel_AB, p_rel_BA, (unsigned*)out);

    proj_mfma_kernel<<<2 * 1563, 256, 0, stream>>>((const short*)out,
                                                   W_out_A, b_out_A, W_out_B, b_out_B,
                                                   x_A, x_B, skip_A, skip_B, out, 1563);
}

// Round 15
// 767.086 us; speedup vs baseline: 1.0358x; 1.0358x over previous
//
#include <hip/hip_runtime.h>
#include <math.h>

#define NA 100000
#define NB 100000
#define NTOT 200000
#define EE 400000      // edges per type
#define TDIM 100       // time encoder dim
#define NTILE (EE / 16)

typedef short bf16x8 __attribute__((ext_vector_type(8)));
typedef float f32x4 __attribute__((ext_vector_type(4)));

// ---------- helpers ----------
__device__ __forceinline__ float gelu_exact(float x) {
    return 0.5f * x * (1.0f + erff(x * 0.70710678118654752f));
}
__device__ __forceinline__ unsigned bf16rne(float f) {
    unsigned u = __float_as_uint(f);
    return (u + 0x7fffu + ((u >> 16) & 1u)) >> 16;
}
__device__ __forceinline__ unsigned pack_bf2(float lo, float hi) {
    return bf16rne(lo) | (bf16rne(hi) << 16);
}
__device__ __forceinline__ float bf_lo(unsigned u) { return __uint_as_float(u << 16); }
__device__ __forceinline__ float bf_hi(unsigned u) { return __uint_as_float(u & 0xffff0000u); }

// ---------- prologue: fusew (0..767) + wedget (768..831) + cnt zero (832..) ----------
__global__ __launch_bounds__(192) void weprep_kernel(
    const float* __restrict__ W_A, const float* __restrict__ b_A,
    const float* __restrict__ W_B, const float* __restrict__ b_B,
    const float* __restrict__ Wk_rel, const float* __restrict__ Wv_rel,
    const float* __restrict__ W_edge,
    unsigned short* __restrict__ WfA, float* __restrict__ bfA,
    unsigned short* __restrict__ WfB, float* __restrict__ bfB,
    unsigned short* __restrict__ Wet, int* __restrict__ cnt)
{
    const int blk = blockIdx.x;
    if (blk < 768) {
        if (threadIdx.x >= 128) return;
        const int et = (blk >= 384) ? 1 : 0;
        const int c = blk - et * 384;
        const int i = threadIdx.x;
        const float* __restrict__ W = et ? W_B : W_A;
        const float* __restrict__ b = et ? b_B : b_A;
        unsigned short* __restrict__ Wf_t = et ? WfB : WfA;
        float* __restrict__ bf = et ? bfB : bfA;

        float acc = 0.f;
        if (c < 128) {
            const int h = c >> 6, e = c & 63;
            const float* __restrict__ Wr = Wk_rel + (long)(h * 2 + et) * 4096;
            for (int d = 0; d < 64; ++d) acc += W[i * 384 + h * 64 + d] * Wr[d * 64 + e];
        } else if (c < 256) {
            acc = W[i * 384 + c];
        } else {
            const int h = (c - 256) >> 6, e = (c - 256) & 63;
            const float* __restrict__ Wr = Wv_rel + (long)(h * 2 + et) * 4096;
            for (int d = 0; d < 64; ++d) acc += W[i * 384 + 256 + h * 64 + d] * Wr[d * 64 + e];
        }
        Wf_t[c * 128 + i] = (unsigned short)bf16rne(acc);
        if (i == 0) {
            float bacc = 0.f;
            if (c < 128) {
                const int h = c >> 6, e = c & 63;
                const float* __restrict__ Wr = Wk_rel + (long)(h * 2 + et) * 4096;
                for (int d = 0; d < 64; ++d) bacc += b[h * 64 + d] * Wr[d * 64 + e];
            } else if (c < 256) {
                bacc = b[c];
            } else {
                const int h = (c - 256) >> 6, e = (c - 256) & 63;
                const float* __restrict__ Wr = Wv_rel + (long)(h * 2 + et) * 4096;
                for (int d = 0; d < 64; ++d) bacc += b[256 + h * 64 + d] * Wr[d * 64 + e];
            }
            bf[c] = bacc;
        }
    } else if (blk < 832) {
        const int col = blk - 768;       // 0..63
        const int k = threadIdx.x;       // 0..191
        const float v = (k < 164) ? W_edge[k * 64 + col] : 0.f;
        Wet[col * 192 + k] = (unsigned short)bf16rne(v);
    } else {
        const int i = (blk - 832) * 192 + threadIdx.x;
        if (i < NTOT) cnt[i] = 0;
    }
}

// ---------- P1 mega-kernel: kqv MFMA || edgefeat wave-MFMA || CSR count ----------
// 21875 blocks = 7 x 3125. role = b%7: {0,1}=kqv, {2..5}=edgefeat, {6}=count.
#define BM 32
__global__ __launch_bounds__(256) void phase1_kernel(
    const float* __restrict__ x_A, const float* __restrict__ x_B,
    const unsigned short* __restrict__ WfA, const unsigned short* __restrict__ WfB,
    const float* __restrict__ bfA, const float* __restrict__ bfB,
    unsigned* __restrict__ q_u32, unsigned* __restrict__ kv_u32,
    const float* __restrict__ lu_A, const float* __restrict__ lu_B,
    const int* __restrict__ eiAB, const int* __restrict__ eiBA,
    const float* __restrict__ t_AB, const float* __restrict__ t_BA,
    const float* __restrict__ msg_AB, const float* __restrict__ msg_BA,
    const float* __restrict__ time_w, const float* __restrict__ time_b,
    const unsigned short* __restrict__ Wet, const float* __restrict__ b_edge,
    unsigned* __restrict__ ef_u32,
    int* __restrict__ cnt)
{
    __shared__ unsigned lds_u[6400];             // 25.6KB union
    const int b = blockIdx.x;
    const int role = b % 7;
    const int sub7 = b / 7;
    const int tid = threadIdx.x;
    const int lane = tid & 63;
    const int wv = tid >> 6;

    if (role < 2) {
        // ================= kqv =================
        const int kblk = sub7 * 2 + role;        // 0..6249
        const bool isA = (kblk < NA / BM);
        const int blk = isA ? kblk : (kblk - NA / BM);
        const float* __restrict__ x = isA ? x_A : x_B;
        const unsigned short* __restrict__ Wf_t = isA ? WfA : WfB;
        const float* __restrict__ bf = isA ? bfA : bfB;
        const int node_off = isA ? 0 : NA;

        unsigned* xs = lds_u;                    // [32][68]
        unsigned* st = lds_u + 2176;             // [32][130]
        const int m = lane & 15;
        const int kq = lane >> 4;
        const int n0 = blk * BM;

        for (int idx = tid; idx < BM * 32; idx += 256) {
            const int n = idx >> 5, j4 = idx & 31;
            const float4 xv = *reinterpret_cast<const float4*>(x + (long)(n0 + n) * 128 + 4 * j4);
            xs[n * 68 + 2 * j4]     = pack_bf2(xv.x, xv.y);
            xs[n * 68 + 2 * j4 + 1] = pack_bf2(xv.z, xv.w);
        }
        __syncthreads();

        const int wq = wv * 96;
        f32x4 acc[2][6];
        #pragma unroll
        for (int mt = 0; mt < 2; ++mt)
            #pragma unroll
            for (int nt = 0; nt < 6; ++nt) acc[mt][nt] = (f32x4){0.f, 0.f, 0.f, 0.f};

        #pragma unroll
        for (int ks = 0; ks < 4; ++ks) {
            bf16x8 a[2], bfr[6];
            #pragma unroll
            for (int mt = 0; mt < 2; ++mt)
                a[mt] = *reinterpret_cast<const bf16x8*>(&xs[(mt * 16 + m) * 68 + ks * 16 + kq * 4]);
            #pragma unroll
            for (int nt = 0; nt < 6; ++nt) {
                const int col = wq + nt * 16 + m;
                bfr[nt] = *reinterpret_cast<const bf16x8*>(Wf_t + (long)col * 128 + ks * 32 + kq * 8);
            }
            #pragma unroll
            for (int mt = 0; mt < 2; ++mt)
                #pragma unroll
                for (int nt = 0; nt < 6; ++nt)
                    acc[mt][nt] = __builtin_amdgcn_mfma_f32_16x16x32_bf16(a[mt], bfr[nt], acc[mt][nt], 0, 0, 0);
        }
        __syncthreads();

        // ---- kv staging pass ----
        #pragma unroll
        for (int nt = 0; nt < 6; ++nt) {
            const int c = wq + nt * 16 + m;
            if (c < 128 || c >= 256) {
                const float bias_c = bf[c];
                const int dw = (c < 128) ? c : (c - 256 + 1);
                #pragma unroll
                for (int mt = 0; mt < 2; ++mt) {
                    #pragma unroll
                    for (int reg = 0; reg < 4; ++reg) {
                        const float v = acc[mt][nt][reg] + bias_c;
                        const float o = __shfl_xor(v, 1);
                        if (!(m & 1)) st[(mt * 16 + kq * 4 + reg) * 130 + dw] = pack_bf2(v, o);
                    }
                }
            }
        }
        __syncthreads();
        {
            const int n = tid >> 3;
            const long nb = node_off + n0 + n;
            const int d0 = (tid & 7) * 16;
            #pragma unroll
            for (int i = 0; i < 4; ++i) {
                uint4 w;
                w.x = st[n * 130 + d0 + i * 4 + 0];
                w.y = st[n * 130 + d0 + i * 4 + 1];
                w.z = st[n * 130 + d0 + i * 4 + 2];
                w.w = st[n * 130 + d0 + i * 4 + 3];
                *reinterpret_cast<uint4*>(kv_u32 + nb * 128 + d0 + i * 4) = w;
            }
        }
        __syncthreads();
        // ---- q staging pass ----
        #pragma unroll
        for (int nt = 0; nt < 6; ++nt) {
            const int c = wq + nt * 16 + m;
            if (c >= 128 && c < 256) {
                const float bias_c = bf[c];
                const int dw = (c - 128) >> 1;
                #pragma unroll
                for (int mt = 0; mt < 2; ++mt) {
                    #pragma unroll
                    for (int reg = 0; reg < 4; ++reg) {
                        const float v = acc[mt][nt][reg] + bias_c;
                        const float o = __shfl_xor(v, 1);
                        if (!(m & 1)) st[(mt * 16 + kq * 4 + reg) * 130 + dw] = pack_bf2(v, o);
                    }
                }
            }
        }
        __syncthreads();
        {
            const int n = tid >> 3;
            const long nb = node_off + n0 + n;
            const int dq = (tid & 7) * 8;
            #pragma unroll
            for (int i = 0; i < 2; ++i) {
                uint4 w;
                w.x = st[n * 130 + dq + i * 4 + 0];
                w.y = st[n * 130 + dq + i * 4 + 1];
                w.z = st[n * 130 + dq + i * 4 + 2];
                w.w = st[n * 130 + dq + i * 4 + 3];
                *reinterpret_cast<uint4*>(q_u32 + nb * 64 + dq + i * 4) = w;
            }
        }
    } else if (role < 6) {
        // ================= edgefeat (wave-synchronous) =================
        const int eblk = sub7 * 4 + (role - 2);
        const int gw = eblk * 4 + wv;
        const bool isAB = gw < NTILE;
        const int tile = isAB ? gw : gw - NTILE;
        const float* __restrict__ lu   = isAB ? lu_A : lu_B;
        const int* __restrict__ ei     = isAB ? eiAB : eiBA;
        const float* __restrict__ tvec = isAB ? t_AB : t_BA;
        const float* __restrict__ msg  = isAB ? msg_AB : msg_BA;
        const long out_off = isAB ? 0L : (long)EE;
        const long e0 = (long)tile * 16;

        unsigned* fw = lds_u + wv * 1600;        // [16][100] per wave

        float rts_l = 0.f;
        if (lane < 16) rts_l = lu[ei[e0 + lane]] - tvec[e0 + lane];

        {
            const int e = lane >> 2, qt = lane & 3;
            const float* mp = msg + (e0 + e) * 64 + qt * 16;
            const float4 a0 = *reinterpret_cast<const float4*>(mp);
            const float4 a1 = *reinterpret_cast<const float4*>(mp + 4);
            const float4 a2 = *reinterpret_cast<const float4*>(mp + 8);
            const float4 a3 = *reinterpret_cast<const float4*>(mp + 12);
            uint2 w0, w1, w2, w3;
            w0.x = pack_bf2(a0.x, a0.y); w0.y = pack_bf2(a0.z, a0.w);
            w1.x = pack_bf2(a1.x, a1.y); w1.y = pack_bf2(a1.z, a1.w);
            w2.x = pack_bf2(a2.x, a2.y); w2.y = pack_bf2(a2.z, a2.w);
            w3.x = pack_bf2(a3.x, a3.y); w3.y = pack_bf2(a3.z, a3.w);
            *reinterpret_cast<uint2*>(&fw[e * 100 + 50 + qt * 8])     = w0;
            *reinterpret_cast<uint2*>(&fw[e * 100 + 50 + qt * 8 + 2]) = w1;
            *reinterpret_cast<uint2*>(&fw[e * 100 + 50 + qt * 8 + 4]) = w2;
            *reinterpret_cast<uint2*>(&fw[e * 100 + 50 + qt * 8 + 6]) = w3;
        }
        #pragma unroll
        for (int i = 0; i < 13; ++i) {
            const int idx = lane + (i << 6);
            if (idx < 800) {
                const int e = idx / 50, j = idx - e * 50;
                const float r = __shfl(rts_l, e);
                const float c0 = __cosf(fmaf(r, time_w[2 * j], time_b[2 * j]));
                const float c1 = __cosf(fmaf(r, time_w[2 * j + 1], time_b[2 * j + 1]));
                fw[e * 100 + j] = pack_bf2(c0, c1);
            }
        }
        #pragma unroll
        for (int i = 0; i < 5; ++i) {
            const int idx = lane + (i << 6);
            if (idx < 288) {
                const int e = idx / 18, j = idx - e * 18;
                fw[e * 100 + 82 + j] = 0u;
            }
        }
        asm volatile("s_waitcnt lgkmcnt(0)" ::: "memory");

        const int m = lane & 15;
        const int kq = lane >> 4;
        f32x4 acc[4];
        #pragma unroll
        for (int nf = 0; nf < 4; ++nf) acc[nf] = (f32x4){0.f, 0.f, 0.f, 0.f};

        #pragma unroll
        for (int ks = 0; ks < 6; ++ks) {
            const bf16x8 a = *reinterpret_cast<const bf16x8*>(&fw[m * 100 + ks * 16 + kq * 4]);
            #pragma unroll
            for (int nf = 0; nf < 4; ++nf) {
                const bf16x8 bb = *reinterpret_cast<const bf16x8*>(Wet + (long)(nf * 16 + m) * 192 + ks * 32 + kq * 8);
                acc[nf] = __builtin_amdgcn_mfma_f32_16x16x32_bf16(a, bb, acc[nf], 0, 0, 0);
            }
        }

        #pragma unroll
        for (int nf = 0; nf < 4; ++nf) {
            const int c = nf * 16 + m;
            const float bc = b_edge[c];
            #pragma unroll
            for (int reg = 0; reg < 4; ++reg) {
                const float v = acc[nf][reg] + bc;
                const float o = __shfl_xor(v, 1);
                if (!(lane & 1)) {
                    const long ee = out_off + e0 + kq * 4 + reg;
                    ef_u32[ee * 32 + (c >> 1)] = pack_bf2(v, o);
                }
            }
        }
    } else {
        // ================= CSR count =================
        const int ee = sub7 * 256 + tid;
        const int dst = (ee < EE) ? (eiAB[EE + ee] + NA) : eiBA[EE + (ee - EE)];
        atomicAdd(&cnt[dst], 1);
    }
}

// ---------- CSR scan ----------
__global__ __launch_bounds__(1024) void scan1_kernel(
    const int* __restrict__ cnt, int* __restrict__ offsets, int* __restrict__ bsum)
{
    __shared__ int tmp[1024];
    const int t = threadIdx.x;
    const int i = blockIdx.x * 1024 + t;
    const int v = (i < NTOT) ? cnt[i] : 0;
    tmp[t] = v;
    __syncthreads();
    for (int off = 1; off < 1024; off <<= 1) {
        const int u = (t >= off) ? tmp[t - off] : 0;
        __syncthreads();
        tmp[t] += u;
        __syncthreads();
    }
    offsets[i] = tmp[t] - v;
    if (t == 1023) bsum[blockIdx.x] = tmp[1023];
}

__global__ __launch_bounds__(256) void scan2_kernel(
    const int* __restrict__ bsum, int* __restrict__ bbase, int nblk)
{
    __shared__ int tmp[256];
    const int t = threadIdx.x;
    const int v = (t < nblk) ? bsum[t] : 0;
    tmp[t] = v;
    __syncthreads();
    for (int off = 1; off < 256; off <<= 1) {
        const int u = (t >= off) ? tmp[t - off] : 0;
        __syncthreads();
        tmp[t] += u;
        __syncthreads();
    }
    bbase[t] = tmp[t] - v;
}

__global__ __launch_bounds__(1024) void scan3_kernel(
    int* __restrict__ offsets, const int* __restrict__ bbase, int* __restrict__ cnt)
{
    const int t = threadIdx.x;
    const int i = blockIdx.x * 1024 + t;
    const int o = offsets[i] + bbase[blockIdx.x];
    offsets[i] = o;
    if (i < NTOT) cnt[i] = o;
    if (blockIdx.x == 0 && t == 0) offsets[NTOT] = 2 * EE;
}

__global__ __launch_bounds__(256) void fill_kernel(
    const int* __restrict__ eiAB, const int* __restrict__ eiBA,
    int* __restrict__ cursor, int2* __restrict__ csr)
{
    const int ee = blockIdx.x * 256 + threadIdx.x;
    if (ee >= 2 * EE) return;
    int src, dst;
    if (ee < EE) { src = eiAB[ee];               dst = eiAB[EE + ee] + NA; }
    else { const int e = ee - EE; src = eiBA[e] + NA; dst = eiBA[EE + e]; }
    const int pos = atomicAdd(&cursor[dst], 1);
    csr[pos] = make_int2(src, ee);
}

// ---------- gather: fused flash-softmax + gelu, 2 edges per wave ----------
// lane = 32*eh + 16*h + j : eh = edge slot, h = head, j = comp group (4 comps)
__global__ __launch_bounds__(256) void gather_kernel(
    const unsigned* __restrict__ qb, const uint4* __restrict__ kv,
    const unsigned* __restrict__ ef,
    const int* __restrict__ offsets, const int2* __restrict__ csr,
    const float* __restrict__ p_rel_AB, const float* __restrict__ p_rel_BA,
    unsigned* __restrict__ g)
{
    const int lane = threadIdx.x & 63;
    const int wv = threadIdx.x >> 6;
    const int eh = lane >> 5;
    const int h = (lane >> 4) & 1;
    const int j = lane & 15;
    const int c = 16 * h + j;                    // dword-pair index 0..31
    const int d0 = blockIdx.x * 16 + wv * 4;     // 12500 blocks, exact
    const float sAB = p_rel_AB[h] * 0.125f;
    const float sBA = p_rel_BA[h] * 0.125f;

    for (int r = 0; r < 4; ++r) {
        const int d = d0 + r;
        const uint2 q2 = *reinterpret_cast<const uint2*>(qb + (long)d * 64 + 2 * c);
        float av0 = 0.f, av1 = 0.f, av2 = 0.f, av3 = 0.f;
        float ae00 = 0.f, ae01 = 0.f, ae10 = 0.f, ae11 = 0.f;
        float den = 0.f;
        const int beg = offsets[d], end = offsets[d + 1];
        for (int p0 = beg; p0 < end; p0 += 2) {
            const int p = p0 + eh;
            const bool valid = (p < end);
            const int2 se = csr[valid ? p : p0];
            const uint4 kvd = kv[(long)se.x * 32 + c];
            float partial = fmaf(bf_lo(q2.x), bf_lo(kvd.x),
                            fmaf(bf_hi(q2.x), bf_hi(kvd.x),
                            fmaf(bf_lo(q2.y), bf_lo(kvd.z),
                                 bf_hi(q2.y) * bf_hi(kvd.z))));
            partial += __shfl_xor(partial, 1);
            partial += __shfl_xor(partial, 2);
            partial += __shfl_xor(partial, 4);
            partial += __shfl_xor(partial, 8);
            const float s = (se.y < EE) ? sAB : sBA;
            float e = valid ? expf(partial * s) : 0.f;
            const unsigned efd = ef[(long)se.y * 32 + c];
            const float ef0 = bf_lo(efd), ef1 = bf_hi(efd);
            const float e_oth = __shfl_xor(e, 16);
            const float w0 = h ? e_oth : e;      // head-0 softmax weight
            const float w1 = h ? e : e_oth;      // head-1 softmax weight
            av0 = fmaf(e, bf_lo(kvd.y), av0);
            av1 = fmaf(e, bf_hi(kvd.y), av1);
            av2 = fmaf(e, bf_lo(kvd.w), av2);
            av3 = fmaf(e, bf_hi(kvd.w), av3);
            ae00 = fmaf(w0, ef0, ae00);
            ae01 = fmaf(w0, ef1, ae01);
            ae10 = fmaf(w1, ef0, ae10);
            ae11 = fmaf(w1, ef1, ae11);
            den += e;
        }
        // merge the two edge-slot halves
        av0 += __shfl_xor(av0, 32);
        av1 += __shfl_xor(av1, 32);
        av2 += __shfl_xor(av2, 32);
        av3 += __shfl_xor(av3, 32);
        ae00 += __shfl_xor(ae00, 32);
        ae01 += __shfl_xor(ae01, 32);
        ae10 += __shfl_xor(ae10, 32);
        ae11 += __shfl_xor(ae11, 32);
        den += __shfl_xor(den, 32);

        const float inv = 1.f / (den + 1e-16f);          // own head's inverse denom
        const float inv_oth = __shfl_xor(inv, 16);
        const float inv0 = h ? inv_oth : inv;
        const float inv1 = h ? inv : inv_oth;

        if (eh == 0) {
            const float gv0 = gelu_exact(av0 * inv);
            const float gv1 = gelu_exact(av1 * inv);
            const float gv2 = gelu_exact(av2 * inv);
            const float gv3 = gelu_exact(av3 * inv);
            const float ge00 = gelu_exact(ae00 * inv0);
            const float ge01 = gelu_exact(ae01 * inv0);
            const float ge10 = gelu_exact(ae10 * inv1);
            const float ge11 = gelu_exact(ae11 * inv1);
            unsigned* gp = g + (long)d * 128;
            const int vb = h ? (64 + 2 * j) : (2 * j);   // v block dword base
            gp[vb]     = pack_bf2(gv0, gv1);
            gp[vb + 1] = pack_bf2(gv2, gv3);
            gp[32 + c] = pack_bf2(ge00, ge01);           // ef, head-0 block
            gp[96 + c] = pack_bf2(ge10, ge11);           // ef, head-1 block
        }
    }
}

// ---------- proj: MFMA out-projection (A and B in one grid), in-place over g ----------
__global__ __launch_bounds__(256) void proj_mfma_kernel(
    const short* __restrict__ g,
    const float* __restrict__ W_out_A, const float* __restrict__ b_out_A,
    const float* __restrict__ W_out_B, const float* __restrict__ b_out_B,
    const float* __restrict__ x_A, const float* __restrict__ x_B,
    const float* __restrict__ skip_A, const float* __restrict__ skip_B,
    float* __restrict__ out, int nblkA)
{
    const bool isA = ((int)blockIdx.x < nblkA);
    const int blk = isA ? blockIdx.x : (blockIdx.x - nblkA);
    const float* __restrict__ W_out = isA ? W_out_A : W_out_B;
    const float* __restrict__ b_out = isA ? b_out_A : b_out_B;
    const float* __restrict__ x = isA ? x_A : x_B;
    const float* __restrict__ skip = isA ? skip_A : skip_B;
    const int roff = isA ? 0 : NA;
    const int N = isA ? NA : NB;

    __shared__ unsigned short Wt[128 * 264];
    const int tid = threadIdx.x;
    const int lane = tid & 63;
    const int wv = tid >> 6;

    for (int idx = tid; idx < 256 * 128; idx += 256) {
        const int k = idx >> 7, n = idx & 127;
        Wt[n * 264 + k] = (unsigned short)bf16rne(W_out[idx]);
    }
    __syncthreads();

    const int m0 = roff + blk * 64 + wv * 16;
    const int rmax = roff + N - 1;
    const float ag = 1.f / (1.f + expf(-skip[0]));

    f32x4 acc[8];
    #pragma unroll
    for (int nf = 0; nf < 8; ++nf) acc[nf] = (f32x4){0.f, 0.f, 0.f, 0.f};

    const int arow = min(m0 + (lane & 15), rmax);
    const int kgrp = (lane >> 4) * 8;

    #pragma unroll
    for (int ks = 0; ks < 8; ++ks) {
        const bf16x8 a = *reinterpret_cast<const bf16x8*>(g + (long)arow * 256 + ks * 32 + kgrp);
        #pragma unroll
        for (int nf = 0; nf < 8; ++nf) {
            const bf16x8 b = *reinterpret_cast<const bf16x8*>(&Wt[(nf * 16 + (lane & 15)) * 264 + ks * 32 + kgrp]);
            acc[nf] = __builtin_amdgcn_mfma_f32_16x16x32_bf16(a, b, acc[nf], 0, 0, 0);
        }
    }

    #pragma unroll
    for (int nf = 0; nf < 8; ++nf) {
        const int col = nf * 16 + (lane & 15);
        const float bc = b_out[col];
        #pragma unroll
        for (int reg = 0; reg < 4; ++reg) {
            const int d = m0 + (lane >> 4) * 4 + reg;
            if (d <= rmax) {
                const float xv = x[(long)(d - roff) * 128 + col];
                out[(long)d * 128 + col] = fmaf(ag, acc[nf][reg] + bc, (1.f - ag) * xv);
            }
        }
    }
}

// ---------- launcher ----------
extern "C" void kernel_launch(void* const* d_in, const int* in_sizes, int n_in,
                              void* d_out, int out_size, void* d_ws, size_t ws_size,
                              hipStream_t stream) {
    const float* x_A     = (const float*)d_in[0];
    const float* x_B     = (const float*)d_in[1];
    const float* lu_A    = (const float*)d_in[2];
    const float* lu_B    = (const float*)d_in[3];
    const float* t_AB    = (const float*)d_in[4];
    const float* t_BA    = (const float*)d_in[5];
    const float* msg_AB  = (const float*)d_in[6];
    const float* msg_BA  = (const float*)d_in[7];
    const float* W_kqv_A = (const float*)d_in[8];
    const float* b_kqv_A = (const float*)d_in[9];
    const float* W_kqv_B = (const float*)d_in[10];
    const float* b_kqv_B = (const float*)d_in[11];
    const float* Wk_rel  = (const float*)d_in[12];
    const float* Wv_rel  = (const float*)d_in[13];
    const float* W_edge  = (const float*)d_in[14];
    const float* b_edge  = (const float*)d_in[15];
    const float* W_out_A = (const float*)d_in[16];
    const float* b_out_A = (const float*)d_in[17];
    const float* W_out_B = (const float*)d_in[18];
    const float* b_out_B = (const float*)d_in[19];
    const float* skip_A  = (const float*)d_in[20];
    const float* skip_B  = (const float*)d_in[21];
    const float* p_rel_AB= (const float*)d_in[22];
    const float* p_rel_BA= (const float*)d_in[23];
    const float* time_w  = (const float*)d_in[24];
    const float* time_b  = (const float*)d_in[25];
    const int*   eiAB    = (const int*)d_in[26];
    const int*   eiBA    = (const int*)d_in[27];
    float* out = (float*)d_out;

    // workspace layout (~264 MB)
    unsigned* q_bf  = (unsigned*)d_ws;                  // 12.8M u32
    unsigned* kvbuf = q_bf + 12800000;                  // 25.6M u32
    unsigned* efbuf = kvbuf + 25600000;                 // 25.6M u32
    int* cnt      = (int*)(efbuf + 25600000);           // 200000
    int* offsets  = cnt + 200000;                       // 210000
    int* csr_base = offsets + 210000;                   // 1.6M ints = 800000 int2
    int2* csr     = (int2*)csr_base;
    unsigned short* WfA = (unsigned short*)(csr_base + 1600000);  // 49152 bf16
    unsigned short* WfB = WfA + 49152;                  // 49152 bf16
    float* bfA    = (float*)(WfB + 49152);              // 384
    float* bfB    = bfA + 384;                          // 384
    int* bsum     = (int*)(bfB + 384);                  // 256
    int* bbase    = bsum + 256;                         // 256
    unsigned short* Wet = (unsigned short*)(bbase + 256); // 12288 bf16

    // prologue: fused weight prep (fusew || wedget || cnt-zero)
    // cnt blocks: ceil(200000/192) = 1042
    weprep_kernel<<<832 + 1042, 192, 0, stream>>>(W_kqv_A, b_kqv_A, W_kqv_B, b_kqv_B,
                                                  Wk_rel, Wv_rel, W_edge,
                                                  WfA, bfA, WfB, bfB, Wet, cnt);

    // P1: kqv || edgefeat || count, co-scheduled (21875 = 7*3125 blocks)
    phase1_kernel<<<21875, 256, 0, stream>>>(x_A, x_B, WfA, WfB, bfA, bfB, q_bf, kvbuf,
                                             lu_A, lu_B, eiAB, eiBA, t_AB, t_BA,
                                             msg_AB, msg_BA, time_w, time_b, Wet, b_edge,
                                             efbuf, cnt);

    // CSR scan + fill
    scan1_kernel<<<196, 1024, 0, stream>>>(cnt, offsets, bsum);
    scan2_kernel<<<1, 256, 0, stream>>>(bsum, bbase, 196);
    scan3_kernel<<<196, 1024, 0, stream>>>(offsets, bbase, cnt);
    fill_kernel<<<(2 * EE + 255) / 256, 256, 0, stream>>>(eiAB, eiBA, cnt, csr);

    gather_kernel<<<NTOT / 16, 256, 0, stream>>>(q_bf, (const uint4*)kvbuf, efbuf,
                                                 offsets, csr,
                                                 p_rel_AB, p_rel_BA, (unsigned*)out);

    proj_mfma_kernel<<<2 * 1563, 256, 0, stream>>>((const short*)out,
                                                   W_out_A, b_out_A, W_out_B, b_out_B,
                                                   x_A, x_B, skip_A, skip_B, out, 1563);
}